// Round 3
// baseline (126.074 us; speedup 1.0000x reference)
//
#include <hip/hip_runtime.h>
#include <math.h>

#define PART_STRIDE 33

__device__ __forceinline__ float fast_atan2f(float y, float x) {
    float ax = fabsf(x), ay = fabsf(y);
    float mx = fmaxf(ax, ay);
    float mn = fminf(ax, ay);
    float a = mn * __builtin_amdgcn_rcpf(fmaxf(mx, 1e-30f));
    float s = a * a;
    float r = fmaf(s, fmaf(s, fmaf(s, fmaf(s, fmaf(s, -0.0117212f, 0.05265332f),
                    -0.11643287f), 0.19354346f), -0.33262347f), 0.99997726f) * a;
    r = (ay > ax) ? (1.57079637f - r) : r;
    r = (x < 0.0f) ? (3.14159274f - r) : r;
    return copysignf(r, y);
}

// 4 waves per patch; wave w owns rows [16w, 16w+16) (+ row 64 for wave 3).
// Lane = column. Rows batch-preloaded into registers (19 loads in flight).
// Row-pool weights are compile-time constants; cross-wave merge via LDS atomics.
__global__ __launch_bounds__(256, 4)
void sift_kernel(const float* __restrict__ in, float* __restrict__ out) {
    __shared__ float part[65 * PART_STRIDE];   // [column][sy*8+a]
    __shared__ float gauss[65];
    __shared__ float c64buf[4][20];            // per-wave col-64 halo rows

    const int tid  = threadIdx.x;
    const int lane = tid & 63;
    const int wid  = tid >> 6;
    const int m    = blockIdx.x;
    const int bc   = m >> 6;
    const int ij   = m & 63;
    const float* src = in + (size_t)bc * (520 * 520) + (ij >> 3) * (65 * 520) + (ij & 7) * 65;

    const int r0 = wid * 16;
    const int nr = (wid == 3) ? 17 : 16;

    // ---- issue all global loads first (latency overlapped with setup) ----
    float rowreg[19];
    #pragma unroll
    for (int k = 0; k < 19; ++k) {
        int rr = r0 - 1 + k;
        rr = (rr < 0) ? 0 : ((rr > 64) ? 64 : rr);
        rowreg[k] = src[rr * 520 + lane];
    }
    if (lane < 19) {
        int rr = r0 - 1 + lane;
        rr = (rr < 0) ? 0 : ((rr > 64) ? 64 : rr);
        c64buf[wid][lane] = src[rr * 520 + 64];
    }
    float xl64 = 0.0f;
    if (lane < nr) xl64 = src[(r0 + lane) * 520 + 63];

    // ---- zero partials ----
    for (int k = tid; k < 65 * PART_STRIDE; k += 256) part[k] = 0.0f;

    // ---- gaussian (wave 0): sigma = 65/sqrt(2) => 2*sigma^2 = 4225 ----
    if (wid == 0) {
        float dd = (float)(lane - 32);
        float e  = __expf(-(dd * dd) * (1.0f / 4225.0f));
        float ssum = e;
        #pragma unroll
        for (int off = 32; off > 0; off >>= 1) ssum += __shfl_xor(ssum, off, 64);
        const float e64c = __expf(-1024.0f / 4225.0f);
        float inv = 1.0f / (ssum + e64c);
        gauss[lane] = e * inv;
        if (lane == 0) gauss[64] = e64c * inv;
    }
    __syncthreads();

    const float gc = gauss[lane];   // column gaussian

    float acc0[8], acc1[8], acc2[8];
    #pragma unroll
    for (int a = 0; a < 8; ++a) { acc0[a] = 0.0f; acc1[a] = 0.0f; acc2[a] = 0.0f; }

    // ---- main 16 rows, fully unrolled (static reg indices, const weights) ----
    #pragma unroll
    for (int k = 0; k < 16; ++k) {
        const float W0 = (3.5f - (float)k) * (1.0f / 13.0f);                  // sy = wid-1 (k<=3)
        const float W1 = (13.0f - fabsf((float)k - 6.5f)) * (1.0f / 13.0f);   // sy = wid
        const float W2 = ((float)k - 9.5f) * (1.0f / 13.0f);                  // sy = wid+1 (k>=10)
        float gr  = gauss[r0 + k];
        float xc  = rowreg[k + 1];
        float xl  = __shfl_up(xc, 1);   if (lane == 0)  xl = xc;
        float c64 = c64buf[wid][k + 1];
        float xr  = __shfl_down(xc, 1); if (lane == 63) xr = c64;
        float gx = 0.5f * (xr - xl);
        float gy = 0.5f * (rowreg[k + 2] - rowreg[k]);
        float mag = sqrtf(fmaf(gx, gx, fmaf(gy, gy, 1e-10f)));
        float ang = fast_atan2f(gy, gx + 1e-10f);
        float o   = fmaf(ang, 1.27323954f, 8.0f);     // in (4,12]
        float bf  = floorf(o);
        float wo1 = o - bf;
        int b0 = (int)bf; b0 = (b0 >= 8) ? b0 - 8 : b0;
        int b1 = (b0 == 7) ? 0 : b0 + 1;
        float magw = mag * gr * gc;
        float q0 = (1.0f - wo1) * magw;
        float q1 = wo1 * magw;
        #pragma unroll
        for (int a = 0; a < 8; ++a) {
            float s = (a == b0) ? q0 : ((a == b1) ? q1 : 0.0f);
            if (k <= 3) {
                acc0[a] = fmaf(s, W0, acc0[a]);
                acc1[a] = fmaf(s, W1, acc1[a]);
            } else if (k < 10) {
                acc1[a] = fmaf(s, W1, acc1[a]);
            } else {
                acc1[a] = fmaf(s, W1, acc1[a]);
                acc2[a] = fmaf(s, W2, acc2[a]);
            }
        }
    }
    // ---- wave 3 extra: row 64 (only window sy=3, weight (13-|16-6.5|)/13) ----
    if (wid == 3) {
        const float W1 = 3.5f * (1.0f / 13.0f);
        float gr  = gauss[64];
        float xc  = rowreg[17];
        float xl  = __shfl_up(xc, 1);   if (lane == 0)  xl = xc;
        float c64 = c64buf[3][17];
        float xr  = __shfl_down(xc, 1); if (lane == 63) xr = c64;
        float gx = 0.5f * (xr - xl);
        float gy = 0.5f * (rowreg[18] - rowreg[16]);
        float mag = sqrtf(fmaf(gx, gx, fmaf(gy, gy, 1e-10f)));
        float ang = fast_atan2f(gy, gx + 1e-10f);
        float o   = fmaf(ang, 1.27323954f, 8.0f);
        float bf  = floorf(o);
        float wo1 = o - bf;
        int b0 = (int)bf; b0 = (b0 >= 8) ? b0 - 8 : b0;
        int b1 = (b0 == 7) ? 0 : b0 + 1;
        float magw = mag * gr * gc;
        float q0 = (1.0f - wo1) * magw;
        float q1 = wo1 * magw;
        #pragma unroll
        for (int a = 0; a < 8; ++a) {
            float s = (a == b0) ? q0 : ((a == b1) ? q1 : 0.0f);
            acc1[a] = fmaf(s, W1, acc1[a]);
        }
    }

    // ---- flush accumulators (cross-wave merge, <=3-way atomic contention) ----
    {
        const int colbase = lane * PART_STRIDE;
        if (wid > 0) {
            #pragma unroll
            for (int a = 0; a < 8; ++a)
                atomicAdd(&part[colbase + (wid - 1) * 8 + a], acc0[a]);
        }
        #pragma unroll
        for (int a = 0; a < 8; ++a)
            atomicAdd(&part[colbase + wid * 8 + a], acc1[a]);
        if (wid < 3) {
            #pragma unroll
            for (int a = 0; a < 8; ++a)
                atomicAdd(&part[colbase + (wid + 1) * 8 + a], acc2[a]);
        }
    }

    // ---- column 64: lane k handles row r0+k ----
    if (lane < nr) {
        int r = r0 + lane;
        float xu = c64buf[wid][lane];
        float xc = c64buf[wid][lane + 1];
        float xd = c64buf[wid][lane + 2];
        float gx = 0.5f * (xc - xl64);          // right neighbor replicates to xc
        float gy = 0.5f * (xd - xu);
        float mag = sqrtf(fmaf(gx, gx, fmaf(gy, gy, 1e-10f)));
        float ang = fast_atan2f(gy, gx + 1e-10f);
        float o   = fmaf(ang, 1.27323954f, 8.0f);
        float bf  = floorf(o);
        float wo1 = o - bf;
        int b0 = (int)bf; b0 = (b0 >= 8) ? b0 - 8 : b0;
        int b1 = (b0 == 7) ? 0 : b0 + 1;
        float magw = mag * gauss[r] * gauss[64];
        float q0 = (1.0f - wo1) * magw;
        float q1 = wo1 * magw;
        int syA = (r + 6) >> 4; if (syA > 3) syA = 3;
        int syB = syA - 1;
        float uA = (float)(r - 16 * syA) + 6.0f;
        float wA = fmaxf(13.0f - fabsf(uA - 12.5f), 0.0f) * (1.0f / 13.0f);
        atomicAdd(&part[64 * PART_STRIDE + syA * 8 + b0], q0 * wA);
        atomicAdd(&part[64 * PART_STRIDE + syA * 8 + b1], q1 * wA);
        if (syB >= 0) {
            float uB = (float)(r - 16 * syB) + 6.0f;
            float wB = fmaxf(13.0f - fabsf(uB - 12.5f), 0.0f) * (1.0f / 13.0f);
            if (wB > 0.0f) {
                atomicAdd(&part[64 * PART_STRIDE + syB * 8 + b0], q0 * wB);
                atomicAdd(&part[64 * PART_STRIDE + syB * 8 + b1], q1 * wB);
            }
        }
    }
    __syncthreads();

    // ---- column pooling + double-normalize + store (wave 0) ----
    if (wid == 0) {
        float v[2];
        #pragma unroll
        for (int h = 0; h < 2; ++h) {
            int o  = lane + h * 64;
            int a  = o >> 4;
            int sy = (o >> 2) & 3;
            int sx = o & 3;
            float s = 0.0f;
            #pragma unroll 2
            for (int k = 0; k < 26; ++k) {
                int c = sx * 16 - 6 + k;
                if ((unsigned)c <= 64u) {
                    float wc = (13.0f - fabsf((float)k - 12.5f)) * (1.0f / 13.0f);
                    s = fmaf(wc, part[c * PART_STRIDE + sy * 8 + a], s);
                }
            }
            v[h] = s;
        }
        float ss = v[0] * v[0] + v[1] * v[1];
        #pragma unroll
        for (int off = 32; off > 0; off >>= 1) ss += __shfl_xor(ss, off, 64);
        float sc = 1.0f / fmaxf(sqrtf(ss), 1e-12f);
        v[0] = fminf(fmaxf(v[0] * sc, 0.0f), 0.2f);
        v[1] = fminf(fmaxf(v[1] * sc, 0.0f), 0.2f);
        ss = v[0] * v[0] + v[1] * v[1];
        #pragma unroll
        for (int off = 32; off > 0; off >>= 1) ss += __shfl_xor(ss, off, 64);
        sc = 1.0f / fmaxf(sqrtf(ss), 1e-12f);
        out[(size_t)m * 128 + lane]      = v[0] * sc;
        out[(size_t)m * 128 + lane + 64] = v[1] * sc;
    }
}

extern "C" void kernel_launch(void* const* d_in, const int* in_sizes, int n_in,
                              void* d_out, int out_size, void* d_ws, size_t ws_size,
                              hipStream_t stream) {
    const float* in = (const float*)d_in[0];
    float* out = (float*)d_out;
    sift_kernel<<<3072, 256, 0, stream>>>(in, out);
}